// Round 1
// baseline (623.489 us; speedup 1.0000x reference)
//
#include <hip/hip_runtime.h>
#include <math.h>

// Problem constants
constexpr int Bn  = 16;
constexpr int Cn  = 256;
constexpr int Mn  = 16384;  // 128*128
constexpr int ICn = 32;

typedef float v4f    __attribute__((ext_vector_type(4)));
typedef short short8 __attribute__((ext_vector_type(8)));

// ---- workspace layout (in floats) ----
// theta bf16 swizzled image: 32*256 ushort = 4096 floats
constexpr size_t OFF_WTH  = 0;
constexpr size_t OFF_TT   = OFF_WTH + 4096;                    // [B][32][32] atomic acc
constexpr size_t OFF_MU   = OFF_TT  + (size_t)Bn * ICn * ICn;  // [B][32] atomic acc
constexpr size_t OFF_BEFF = OFF_MU  + (size_t)Bn * ICn;        // [B][256] folded bias
constexpr size_t OFF_WIMG = OFF_BEFF + (size_t)Bn * Cn;        // [B][256][256] ushort swizzled W_eff

__device__ inline unsigned short f2bf(float f) {
    unsigned u = __float_as_uint(f);
    u += 0x7fffu + ((u >> 16) & 1u);   // RNE (inputs finite)
    return (unsigned short)(u >> 16);
}

__device__ inline void gload_lds16(const void* g, void* l) {
    __builtin_amdgcn_global_load_lds(
        (const __attribute__((address_space(1))) unsigned int*)g,
        (__attribute__((address_space(3))) unsigned int*)l,
        16, 0, 0);
}

// ---------------- K0: theta_w -> bf16, swizzled image ----------------
// Ws[row][slot*8 + (k&7)] where slot = (k>>3) ^ (row&7).
__global__ void k0_prep_w(const float* __restrict__ th_w,
                          unsigned short* __restrict__ wbf) {
    int idx = blockIdx.x * 256 + threadIdx.x;   // 8192
    int row = idx >> 8, ks = idx & 255;
    int slot = ks >> 3;
    int k = ((slot ^ (row & 7)) << 3) | (ks & 7);
    wbf[idx] = f2bf(th_w[row * Cn + k]);
}

// ---------------- K1: theta projection + covariance stats only ----------------
// Grid (M/64, B), 256 threads (4 waves). Wave w owns px [16w,16w+16), 32 theta rows.
__global__ __launch_bounds__(256, 4) void k1_stats(
    const float* __restrict__ x,
    const unsigned short* __restrict__ wbf,
    const float* __restrict__ theta_b,
    float* __restrict__ tt,
    float* __restrict__ mu)
{
    __shared__ __align__(16) unsigned short Ws[32 * 256];  // 16 KB, swizzled
    __shared__ __align__(16) unsigned short Ts[32 * 72];   // t tile bf16, pad 72
    __shared__ float mu_s[ICn];

    const int tx   = threadIdx.x;
    const int b    = blockIdx.y;
    const int m0   = blockIdx.x * 64;
    const int lane = tx & 63;
    const int w    = tx >> 6;       // wave 0..3
    const int ln15 = lane & 15;
    const int q    = lane >> 4;     // quad 0..3

    // theta W image: global -> LDS verbatim, 16 KB
    {
        const int4* src = (const int4*)wbf;
        int4* dst = (int4*)Ws;
        #pragma unroll
        for (int i = 0; i < 4; ++i) dst[tx + 256 * i] = src[tx + 256 * i];
    }
    if (tx < ICn) mu_s[tx] = 0.f;
    __syncthreads();

    v4f acc[2];
    #pragma unroll
    for (int nt = 0; nt < 2; ++nt) acc[nt] = (v4f){0.f, 0.f, 0.f, 0.f};

    // A-frag source: lane -> px = m0 + 16w + ln15, k = kc*32 + q*8 + j
    const float* xbase = x + ((size_t)b * Cn + q * 8) * Mn + m0 + w * 16 + ln15;

    float xf[8];
    #pragma unroll
    for (int j = 0; j < 8; ++j) xf[j] = xbase[(size_t)j * Mn];

    #pragma unroll
    for (int kc = 0; kc < 8; ++kc) {
        short8 a;
        #pragma unroll
        for (int j = 0; j < 8; ++j) a[j] = (short)f2bf(xf[j]);
        if (kc < 7) {
            #pragma unroll
            for (int j = 0; j < 8; ++j)
                xf[j] = xbase[(size_t)((kc + 1) * 32 + j) * Mn];
        }
        #pragma unroll
        for (int nt = 0; nt < 2; ++nt) {
            int row  = nt * 16 + ln15;
            int slot = (kc * 4 + q) ^ (row & 7);
            short8 bf = *(const short8*)&Ws[row * 256 + slot * 8];
            acc[nt] = __builtin_amdgcn_mfma_f32_16x16x32_bf16(a, bf, acc[nt], 0, 0, 0);
        }
    }

    // ---- epilogue: theta rows -> Ts (bf16) + mu partials ----
    // D layout: n(col)=ln15 -> row, m=(q*4+reg) -> px_local = 16w + q*4 + reg.
    #pragma unroll
    for (int nt = 0; nt < 2; ++nt) {
        int tr = nt * 16 + ln15;
        float bb = theta_b[tr];
        float s = 0.f;
        #pragma unroll
        for (int r = 0; r < 4; ++r) {
            float tv = acc[nt][r] + bb;
            Ts[tr * 72 + w * 16 + q * 4 + r] = f2bf(tv);
            s += tv;
        }
        s += __shfl_xor(s, 16);
        s += __shfl_xor(s, 32);
        if (q == 0) atomicAdd(&mu_s[tr], s);
    }
    __syncthreads();

    // tt += T T^T over this block's 64 px (MFMA, both frags same pattern)
    {
        int i0 = (w & 1) * 16, j0 = (w >> 1) * 16;
        v4f at = (v4f){0.f, 0.f, 0.f, 0.f};
        #pragma unroll
        for (int pc = 0; pc < 2; ++pc) {
            short8 A  = *(const short8*)&Ts[(i0 + ln15) * 72 + pc * 32 + q * 8];
            short8 Bv = *(const short8*)&Ts[(j0 + ln15) * 72 + pc * 32 + q * 8];
            at = __builtin_amdgcn_mfma_f32_16x16x32_bf16(A, Bv, at, 0, 0, 0);
        }
        float* ttb = tt + (size_t)b * ICn * ICn;
        #pragma unroll
        for (int r = 0; r < 4; ++r)
            atomicAdd(&ttb[(i0 + q * 4 + r) * ICn + j0 + ln15], at[r]);
    }
    if (tx < ICn) atomicAdd(&mu[b * ICn + tx], mu_s[tx]);
}

// ---------------- K2: sigma -> softmax -> fold W_eff = w_w@attn@g_w ----------------
// Grid (B, 4): each block computes all 256 rows of W_eff for one 64-wide k chunk,
// writing the bf16 swizzled image directly. Chunk 0 also emits b_eff.
__global__ void k2_fold(const float* __restrict__ tt,
                        const float* __restrict__ mu_in,
                        const float* __restrict__ g_w,
                        const float* __restrict__ g_b,
                        const float* __restrict__ w_w,
                        const float* __restrict__ w_b,
                        unsigned short* __restrict__ wimg,
                        float* __restrict__ beff)
{
    __shared__ float s_mu[ICn];
    __shared__ float s_sig[ICn][ICn];
    __shared__ float s_attn[ICn][ICn + 1];
    __shared__ float s_gw[ICn][64];
    __shared__ float s_gb[ICn];

    const int b  = blockIdx.x;
    const int kc = blockIdx.y;      // k chunk 0..3 (64 wide)
    const int tx = threadIdx.x;

    if (tx < ICn) s_mu[tx] = mu_in[b * ICn + tx] * (1.f / Mn);
    __syncthreads();

    for (int p = tx; p < ICn * ICn; p += 256) {
        int i = p >> 5, j = p & 31;
        s_sig[i][j] = (tt[b * ICn * ICn + p] * (1.f / Mn) - s_mu[i] * s_mu[j])
                      * 0.17677669529663687f;  // 1/sqrt(32)
    }
    // stage g_w chunk (fp32) + g_b
    for (int p = tx; p < ICn * 64; p += 256) {
        int j = p >> 6, kk = p & 63;
        s_gw[j][kk] = g_w[j * Cn + kc * 64 + kk];
    }
    if (tx < ICn) s_gb[tx] = g_b[tx];
    __syncthreads();

    if (tx < ICn) {
        float mx = -1e30f;
        #pragma unroll
        for (int j = 0; j < ICn; ++j) mx = fmaxf(mx, s_sig[tx][j]);
        float e[ICn];
        float sum = 0.f;
        #pragma unroll
        for (int j = 0; j < ICn; ++j) { e[j] = __expf(s_sig[tx][j] - mx); sum += e[j]; }
        float r = 1.f / sum;
        #pragma unroll
        for (int j = 0; j < ICn; ++j) s_attn[tx][j] = e[j] * r;
    }
    __syncthreads();

    const int c = tx;
    float wr[ICn];
    #pragma unroll
    for (int i = 0; i < ICn; i += 4) {
        float4 v = *(const float4*)(w_w + c * ICn + i);
        wr[i] = v.x; wr[i + 1] = v.y; wr[i + 2] = v.z; wr[i + 3] = v.w;
    }
    // a2 = (w_w @ attn) row c
    float a2[ICn];
    #pragma unroll
    for (int j = 0; j < ICn; ++j) {
        float s = 0.f;
        #pragma unroll
        for (int i = 0; i < ICn; ++i) s += wr[i] * s_attn[i][j];
        a2[j] = s;
    }
    // W_eff[c][k] = sum_j a2[j] * g_w[j][k], written bf16-swizzled
    unsigned short* wrow = wimg + ((size_t)b * Cn + c) * Cn;
    for (int kk = 0; kk < 64; ++kk) {
        int k = kc * 64 + kk;
        float v = 0.f;
        #pragma unroll
        for (int j = 0; j < ICn; ++j) v += a2[j] * s_gw[j][kk];
        int pos = (((k >> 3) ^ (c & 7)) << 3) | (k & 7);
        wrow[pos] = f2bf(v);
    }
    if (kc == 0) {
        float s = 0.f;
        #pragma unroll
        for (int i = 0; i < ICn; ++i) {
            float ab = 0.f;
            #pragma unroll
            for (int j = 0; j < ICn; ++j) ab += s_attn[i][j] * s_gb[j];
            s += wr[i] * ab;
        }
        beff[b * Cn + c] = s + w_b[c];
    }
}

// ---------------- K3: out = W_eff @ x + b_eff + x (bf16 MFMA) ----------------
// Grid (M/64, B), 256 threads (4 waves). Wave w owns px [16w,16w+16), all 256 c,
// processed as two 128-row W_eff chunks staged in LDS. x frags live in registers.
__global__ __launch_bounds__(256, 2) void k3_out(
    const float* __restrict__ x,
    const unsigned short* __restrict__ wimg,
    const float* __restrict__ beff,
    float* __restrict__ out)
{
    __shared__ __align__(16) unsigned short Ws[128 * 256];  // 64 KB, swizzled chunk
    __shared__ float bb[Cn];

    const int tx   = threadIdx.x;
    const int b    = blockIdx.y;
    const int m0   = blockIdx.x * 64;
    const int lane = tx & 63;
    const int w    = tx >> 6;
    const int ln15 = lane & 15;
    const int q    = lane >> 4;

    const char* gw0 = (const char*)(wimg + (size_t)b * Cn * Cn);  // batch image, bytes

    // async stage chunk 0 (rows 0..127) -> LDS, 64 segments of 1 KB
    #pragma unroll
    for (int i = 0; i < 16; ++i) {
        int seg = w * 16 + i;
        gload_lds16(gw0 + seg * 1024 + lane * 16, (char*)Ws + seg * 1024);
    }
    if (tx < 64) ((float4*)bb)[tx] = ((const float4*)(beff + b * Cn))[tx];

    // x frags: lane -> px = m0 + 16w + ln15, k = kc*32 + q*8 + j (kept in regs)
    const float* xbase = x + ((size_t)b * Cn + q * 8) * Mn + m0 + w * 16 + ln15;
    short8 a[8];
    #pragma unroll
    for (int kc = 0; kc < 8; ++kc) {
        float xf[8];
        #pragma unroll
        for (int j = 0; j < 8; ++j) xf[j] = xbase[(size_t)(kc * 32 + j) * Mn];
        #pragma unroll
        for (int j = 0; j < 8; ++j) a[kc][j] = (short)f2bf(xf[j]);
    }
    __syncthreads();   // drains vmcnt -> chunk 0 resident

    const size_t obase = (size_t)b * Cn * Mn + m0 + w * 16 + q * 4;
    v4f acc[8];

    // ---- chunk 0: c in [0,128) ----
    #pragma unroll
    for (int ct = 0; ct < 8; ++ct) acc[ct] = (v4f){0.f, 0.f, 0.f, 0.f};
    #pragma unroll
    for (int kc = 0; kc < 8; ++kc) {
        #pragma unroll
        for (int ct = 0; ct < 8; ++ct) {
            int row  = ct * 16 + ln15;
            int slot = (kc * 4 + q) ^ (row & 7);
            short8 bf = *(const short8*)&Ws[row * 256 + slot * 8];
            acc[ct] = __builtin_amdgcn_mfma_f32_16x16x32_bf16(a[kc], bf, acc[ct], 0, 0, 0);
        }
    }
    __syncthreads();   // all waves done reading chunk 0

    // async stage chunk 1 (rows 128..255) while we run epilogue 0
    #pragma unroll
    for (int i = 0; i < 16; ++i) {
        int seg = w * 16 + i;
        gload_lds16(gw0 + 65536 + seg * 1024 + lane * 16, (char*)Ws + seg * 1024);
    }
    // epilogue chunk 0: residual (fp32, L1/L2-hot) + bias + store
    #pragma unroll
    for (int ct = 0; ct < 8; ++ct) {
        int c = ct * 16 + ln15;
        float4 xv = *(const float4*)(x + obase + (size_t)c * Mn);
        float wb = bb[c];
        float4 o;
        o.x = acc[ct][0] + xv.x + wb;
        o.y = acc[ct][1] + xv.y + wb;
        o.z = acc[ct][2] + xv.z + wb;
        o.w = acc[ct][3] + xv.w + wb;
        *(float4*)(out + obase + (size_t)c * Mn) = o;
    }
    __syncthreads();   // drains vmcnt -> chunk 1 resident

    // ---- chunk 1: c in [128,256) ----
    #pragma unroll
    for (int ct = 0; ct < 8; ++ct) acc[ct] = (v4f){0.f, 0.f, 0.f, 0.f};
    #pragma unroll
    for (int kc = 0; kc < 8; ++kc) {
        #pragma unroll
        for (int ct = 0; ct < 8; ++ct) {
            int row  = ct * 16 + ln15;       // local row; (128+row)&7 == row&7
            int slot = (kc * 4 + q) ^ (row & 7);
            short8 bf = *(const short8*)&Ws[row * 256 + slot * 8];
            acc[ct] = __builtin_amdgcn_mfma_f32_16x16x32_bf16(a[kc], bf, acc[ct], 0, 0, 0);
        }
    }
    #pragma unroll
    for (int ct = 0; ct < 8; ++ct) {
        int c = 128 + ct * 16 + ln15;
        float4 xv = *(const float4*)(x + obase + (size_t)c * Mn);
        float wb = bb[c];
        float4 o;
        o.x = acc[ct][0] + xv.x + wb;
        o.y = acc[ct][1] + xv.y + wb;
        o.z = acc[ct][2] + xv.z + wb;
        o.w = acc[ct][3] + xv.w + wb;
        *(float4*)(out + obase + (size_t)c * Mn) = o;
    }
}

extern "C" void kernel_launch(void* const* d_in, const int* in_sizes, int n_in,
                              void* d_out, int out_size, void* d_ws, size_t ws_size,
                              hipStream_t stream) {
    const float* x    = (const float*)d_in[0];
    const float* g_w  = (const float*)d_in[1];
    const float* g_b  = (const float*)d_in[2];
    const float* th_w = (const float*)d_in[3];
    const float* th_b = (const float*)d_in[4];
    const float* w_w  = (const float*)d_in[5];
    const float* w_b  = (const float*)d_in[6];
    float* out = (float*)d_out;
    float* ws  = (float*)d_ws;

    unsigned short* wth  = (unsigned short*)(ws + OFF_WTH);
    float* tt            = ws + OFF_TT;
    float* mu            = ws + OFF_MU;
    float* beff          = ws + OFF_BEFF;
    unsigned short* wimg = (unsigned short*)(ws + OFF_WIMG);

    // zero atomic accumulators (tt and mu contiguous)
    hipMemsetAsync(tt, 0, (size_t)(Bn * ICn * ICn + Bn * ICn) * sizeof(float), stream);

    k0_prep_w<<<32, 256, 0, stream>>>(th_w, wth);
    k1_stats<<<dim3(Mn / 64, Bn), 256, 0, stream>>>(x, wth, th_b, tt, mu);
    k2_fold<<<dim3(Bn, 4), 256, 0, stream>>>(tt, mu, g_w, g_b, w_w, w_b, wimg, beff);
    k3_out<<<dim3(Mn / 64, Bn), 256, 0, stream>>>(x, wimg, beff, out);
}

// Round 2
// 610.448 us; speedup vs baseline: 1.0214x; 1.0214x over previous
//
#include <hip/hip_runtime.h>
#include <math.h>

// Problem constants
constexpr int Bn  = 16;
constexpr int Cn  = 256;
constexpr int Mn  = 16384;  // 128*128
constexpr int ICn = 32;

typedef float v4f    __attribute__((ext_vector_type(4)));
typedef short short8 __attribute__((ext_vector_type(8)));

// ---- workspace layout (in floats) ----
constexpr size_t OFF_WTH  = 0;                                 // theta bf16 swizzled image (8192 ushort)
constexpr size_t OFF_TT   = OFF_WTH + 4096;                    // [B][32][32] atomic acc
constexpr size_t OFF_MU   = OFF_TT  + (size_t)Bn * ICn * ICn;  // [B][32] atomic acc
constexpr size_t OFF_BEFF = OFF_MU  + (size_t)Bn * ICn;        // [B][256] folded bias
constexpr size_t OFF_WIMG = OFF_BEFF + (size_t)Bn * Cn;        // [B][256][256] ushort swizzled W_eff

__device__ inline unsigned short f2bf(float f) {
    unsigned u = __float_as_uint(f);
    u += 0x7fffu + ((u >> 16) & 1u);   // RNE (inputs finite)
    return (unsigned short)(u >> 16);
}

__device__ inline void gload_lds16(const void* g, void* l) {
    __builtin_amdgcn_global_load_lds(
        (const __attribute__((address_space(1))) unsigned int*)g,
        (__attribute__((address_space(3))) unsigned int*)l,
        16, 0, 0);
}

// ---------------- K0: theta_w -> bf16, swizzled image ----------------
// Ws[row][slot*8 + (k&7)] where slot = (k>>3) ^ (row&7).
__global__ void k0_prep_w(const float* __restrict__ th_w,
                          unsigned short* __restrict__ wbf) {
    int idx = blockIdx.x * 256 + threadIdx.x;   // 8192
    int row = idx >> 8, ks = idx & 255;
    int slot = ks >> 3;
    int k = ((slot ^ (row & 7)) << 3) | (ks & 7);
    wbf[idx] = f2bf(th_w[row * Cn + k]);
}

// ======= shared pattern: coalesced x-tile load + 4x4 reg transpose ->
// XOR-swizzled bf16 LDS tile Xs[64 px][256 c].
// Value (px,c) lives at byte px*512 + ((c*2) ^ ((px&7)<<4)).
// Writer: 16 float4 coalesced global loads, 16 ds_write_b64 (~2-way, free).
// Reader (MFMA A-frag): lane(q,ln15,w): px=16w+ln15, a[kc] = 16B granule at
// px*512 + ((kc*64+q*16) ^ ((px&7)<<4)) -> conflict-free ds_read_b128.
__device__ inline void load_transpose_x(const float* __restrict__ xb,
                                        unsigned short* Xs, int tx) {
    #pragma unroll
    for (int i = 0; i < 4; ++i) {
        int c0  = i * 64 + (tx >> 4) * 4;
        int px0 = (tx & 15) * 4;
        v4f v[4];
        #pragma unroll
        for (int cc = 0; cc < 4; ++cc)
            v[cc] = *(const v4f*)(xb + (size_t)(c0 + cc) * Mn + px0);
        #pragma unroll
        for (int r = 0; r < 4; ++r) {
            int px = px0 + r;
            unsigned long long pk =
                  (unsigned long long)f2bf(v[0][r])
                | ((unsigned long long)f2bf(v[1][r]) << 16)
                | ((unsigned long long)f2bf(v[2][r]) << 32)
                | ((unsigned long long)f2bf(v[3][r]) << 48);
            *(unsigned long long*)((char*)Xs + px * 512 + ((c0 * 2) ^ ((px & 7) << 4))) = pk;
        }
    }
}

// ---------------- K1: theta projection + covariance stats ----------------
// Grid (M/64, B), 256 threads (4 waves). Wave w owns px [16w,16w+16).
__global__ __launch_bounds__(256, 3) void k1_stats(
    const float* __restrict__ x,
    const unsigned short* __restrict__ wbf,
    const float* __restrict__ theta_b,
    float* __restrict__ tt,
    float* __restrict__ mu)
{
    __shared__ __align__(16) unsigned short Xs[64 * 256];  // 32 KB x tile
    __shared__ __align__(16) unsigned short Ws[32 * 256];  // 16 KB theta, swizzled
    __shared__ __align__(16) unsigned short Ts[32 * 72];   // t tile bf16, pad 72
    __shared__ float mu_s[ICn];

    const int tx   = threadIdx.x;
    const int b    = blockIdx.y;
    const int m0   = blockIdx.x * 64;
    const int lane = tx & 63;
    const int w    = tx >> 6;       // wave 0..3
    const int ln15 = lane & 15;
    const int q    = lane >> 4;     // quad 0..3

    // theta W image: async global -> LDS, 16 KB
    #pragma unroll
    for (int i = 0; i < 4; ++i) {
        int seg = w * 4 + i;
        gload_lds16((const char*)wbf + seg * 1024 + lane * 16, (char*)Ws + seg * 1024);
    }

    // x tile: coalesced load + transpose into Xs
    const float* xb = x + (size_t)b * Cn * Mn + m0;
    load_transpose_x(xb, Xs, tx);

    if (tx < ICn) mu_s[tx] = 0.f;
    __syncthreads();   // drains gload_lds (vmcnt) + ds_writes (lgkmcnt)

    // A-frags from Xs
    short8 a[8];
    {
        int px = w * 16 + ln15;
        #pragma unroll
        for (int kc = 0; kc < 8; ++kc)
            a[kc] = *(const short8*)((const char*)Xs + px * 512
                                     + ((kc * 64 + q * 16) ^ ((px & 7) << 4)));
    }

    v4f acc[2];
    #pragma unroll
    for (int nt = 0; nt < 2; ++nt) acc[nt] = (v4f){0.f, 0.f, 0.f, 0.f};

    #pragma unroll
    for (int kc = 0; kc < 8; ++kc) {
        #pragma unroll
        for (int nt = 0; nt < 2; ++nt) {
            int row  = nt * 16 + ln15;
            int slot = (kc * 4 + q) ^ (row & 7);
            short8 bf = *(const short8*)&Ws[row * 256 + slot * 8];
            acc[nt] = __builtin_amdgcn_mfma_f32_16x16x32_bf16(a[kc], bf, acc[nt], 0, 0, 0);
        }
    }

    // ---- epilogue: theta rows -> Ts (bf16) + mu partials ----
    // D layout: n(col)=ln15 -> row, m=(q*4+reg) -> px_local = 16w + q*4 + reg.
    #pragma unroll
    for (int nt = 0; nt < 2; ++nt) {
        int tr = nt * 16 + ln15;
        float bbv = theta_b[tr];
        float s = 0.f;
        #pragma unroll
        for (int r = 0; r < 4; ++r) {
            float tv = acc[nt][r] + bbv;
            Ts[tr * 72 + w * 16 + q * 4 + r] = f2bf(tv);
            s += tv;
        }
        s += __shfl_xor(s, 16);
        s += __shfl_xor(s, 32);
        if (q == 0) atomicAdd(&mu_s[tr], s);
    }
    __syncthreads();

    // tt += T T^T over this block's 64 px (MFMA, both frags same pattern)
    {
        int i0 = (w & 1) * 16, j0 = (w >> 1) * 16;
        v4f at = (v4f){0.f, 0.f, 0.f, 0.f};
        #pragma unroll
        for (int pc = 0; pc < 2; ++pc) {
            short8 A  = *(const short8*)&Ts[(i0 + ln15) * 72 + pc * 32 + q * 8];
            short8 Bv = *(const short8*)&Ts[(j0 + ln15) * 72 + pc * 32 + q * 8];
            at = __builtin_amdgcn_mfma_f32_16x16x32_bf16(A, Bv, at, 0, 0, 0);
        }
        float* ttb = tt + (size_t)b * ICn * ICn;
        #pragma unroll
        for (int r = 0; r < 4; ++r)
            atomicAdd(&ttb[(i0 + q * 4 + r) * ICn + j0 + ln15], at[r]);
    }
    if (tx < ICn) atomicAdd(&mu[b * ICn + tx], mu_s[tx]);
}

// ---------------- K2: sigma -> softmax -> fold W_eff = w_w@attn@g_w ----------------
__global__ void k2_fold(const float* __restrict__ tt,
                        const float* __restrict__ mu_in,
                        const float* __restrict__ g_w,
                        const float* __restrict__ g_b,
                        const float* __restrict__ w_w,
                        const float* __restrict__ w_b,
                        unsigned short* __restrict__ wimg,
                        float* __restrict__ beff)
{
    __shared__ float s_mu[ICn];
    __shared__ float s_sig[ICn][ICn];
    __shared__ float s_attn[ICn][ICn + 1];
    __shared__ float s_gw[ICn][64];
    __shared__ float s_gb[ICn];

    const int b  = blockIdx.x;
    const int kc = blockIdx.y;      // k chunk 0..3 (64 wide)
    const int tx = threadIdx.x;

    if (tx < ICn) s_mu[tx] = mu_in[b * ICn + tx] * (1.f / Mn);
    __syncthreads();

    for (int p = tx; p < ICn * ICn; p += 256) {
        int i = p >> 5, j = p & 31;
        s_sig[i][j] = (tt[b * ICn * ICn + p] * (1.f / Mn) - s_mu[i] * s_mu[j])
                      * 0.17677669529663687f;  // 1/sqrt(32)
    }
    for (int p = tx; p < ICn * 64; p += 256) {
        int j = p >> 6, kk = p & 63;
        s_gw[j][kk] = g_w[j * Cn + kc * 64 + kk];
    }
    if (tx < ICn) s_gb[tx] = g_b[tx];
    __syncthreads();

    if (tx < ICn) {
        float mx = -1e30f;
        #pragma unroll
        for (int j = 0; j < ICn; ++j) mx = fmaxf(mx, s_sig[tx][j]);
        float e[ICn];
        float sum = 0.f;
        #pragma unroll
        for (int j = 0; j < ICn; ++j) { e[j] = __expf(s_sig[tx][j] - mx); sum += e[j]; }
        float r = 1.f / sum;
        #pragma unroll
        for (int j = 0; j < ICn; ++j) s_attn[tx][j] = e[j] * r;
    }
    __syncthreads();

    const int c = tx;
    float wr[ICn];
    #pragma unroll
    for (int i = 0; i < ICn; i += 4) {
        float4 v = *(const float4*)(w_w + c * ICn + i);
        wr[i] = v.x; wr[i + 1] = v.y; wr[i + 2] = v.z; wr[i + 3] = v.w;
    }
    float a2[ICn];
    #pragma unroll
    for (int j = 0; j < ICn; ++j) {
        float s = 0.f;
        #pragma unroll
        for (int i = 0; i < ICn; ++i) s += wr[i] * s_attn[i][j];
        a2[j] = s;
    }
    unsigned short* wrow = wimg + ((size_t)b * Cn + c) * Cn;
    for (int kk = 0; kk < 64; ++kk) {
        int k = kc * 64 + kk;
        float v = 0.f;
        #pragma unroll
        for (int j = 0; j < ICn; ++j) v += a2[j] * s_gw[j][kk];
        int pos = (((k >> 3) ^ (c & 7)) << 3) | (k & 7);
        wrow[pos] = f2bf(v);
    }
    if (kc == 0) {
        float s = 0.f;
        #pragma unroll
        for (int i = 0; i < ICn; ++i) {
            float ab = 0.f;
            #pragma unroll
            for (int j = 0; j < ICn; ++j) ab += s_attn[i][j] * s_gb[j];
            s += wr[i] * ab;
        }
        beff[b * Cn + c] = s + w_b[c];
    }
}

// ---------------- K3: out = W_eff @ x + b_eff + x (bf16 MFMA) ----------------
// Grid (M/64, B), 256 threads (4 waves), 4 blocks/CU.
// Phase A: coalesced x load -> LDS transpose -> A-frags in regs (LDS freed).
// Then 4 chunks of 64 W_eff rows staged into the SAME 32 KB via gload_lds;
// residual float4 reads are L2-hot (loader already streamed the tile).
__global__ __launch_bounds__(256, 4) void k3_out(
    const float* __restrict__ x,
    const unsigned short* __restrict__ wimg,
    const float* __restrict__ beff,
    float* __restrict__ out)
{
    __shared__ __align__(16) unsigned short Xs[64 * 256];  // 32 KB: x tile, then W chunks
    __shared__ float bb[Cn];

    const int tx   = threadIdx.x;
    const int b    = blockIdx.y;
    const int m0   = blockIdx.x * 64;
    const int lane = tx & 63;
    const int w    = tx >> 6;
    const int ln15 = lane & 15;
    const int q    = lane >> 4;

    const float* xb = x + (size_t)b * Cn * Mn + m0;

    // phase A: x tile -> Xs (coalesced + transpose)
    load_transpose_x(xb, Xs, tx);
    if (tx < 64) ((float4*)bb)[tx] = ((const float4*)(beff + b * Cn))[tx];

    // residual prefetch for chunk 0 (lines L2-hot from loader)
    const size_t obase = (size_t)b * Cn * Mn + m0 + w * 16 + q * 4;
    v4f xv[4];
    #pragma unroll
    for (int ct = 0; ct < 4; ++ct)
        xv[ct] = *(const v4f*)(x + obase + (size_t)(ct * 16 + ln15) * Mn);

    __syncthreads();   // Xs (x tile) ready

    // A-frags to registers
    short8 a[8];
    {
        int px = w * 16 + ln15;
        #pragma unroll
        for (int kc = 0; kc < 8; ++kc)
            a[kc] = *(const short8*)((const char*)Xs + px * 512
                                     + ((kc * 64 + q * 16) ^ ((px & 7) << 4)));
    }
    __syncthreads();   // all frag reads done; Xs reusable for W

    const char* gw0 = (const char*)(wimg + (size_t)b * Cn * Cn);  // batch W image

    // stage W chunk 0 (rows 0..63, 32 KB)
    #pragma unroll
    for (int i = 0; i < 8; ++i) {
        int seg = w * 8 + i;
        gload_lds16(gw0 + seg * 1024 + lane * 16, (char*)Xs + seg * 1024);
    }
    __syncthreads();   // chunk 0 resident (vmcnt drained by barrier)

    #pragma unroll
    for (int n = 0; n < 4; ++n) {
        v4f acc[4];
        #pragma unroll
        for (int ct = 0; ct < 4; ++ct) acc[ct] = (v4f){0.f, 0.f, 0.f, 0.f};
        #pragma unroll
        for (int kc = 0; kc < 8; ++kc) {
            #pragma unroll
            for (int ct = 0; ct < 4; ++ct) {
                int row  = ct * 16 + ln15;     // local row within chunk; (64n+row)&7 == row&7
                int slot = (kc * 4 + q) ^ (row & 7);
                short8 bf = *(const short8*)&Xs[row * 256 + slot * 8];
                acc[ct] = __builtin_amdgcn_mfma_f32_16x16x32_bf16(a[kc], bf, acc[ct], 0, 0, 0);
            }
        }
        __syncthreads();   // all waves done reading chunk n

        if (n < 3) {
            // stage chunk n+1 (overlaps epilogue below)
            #pragma unroll
            for (int i = 0; i < 8; ++i) {
                int seg = w * 8 + i;
                gload_lds16(gw0 + (size_t)(n + 1) * 32768 + seg * 1024 + lane * 16,
                            (char*)Xs + seg * 1024);
            }
        }

        // epilogue chunk n: residual + bias + store
        #pragma unroll
        for (int ct = 0; ct < 4; ++ct) {
            int c = n * 64 + ct * 16 + ln15;
            float wb2 = bb[c];
            v4f o;
            o[0] = acc[ct][0] + xv[ct][0] + wb2;
            o[1] = acc[ct][1] + xv[ct][1] + wb2;
            o[2] = acc[ct][2] + xv[ct][2] + wb2;
            o[3] = acc[ct][3] + xv[ct][3] + wb2;
            *(v4f*)(out + obase + (size_t)c * Mn) = o;
        }

        if (n < 3) {
            // residual prefetch for chunk n+1 (hides under barrier + next MFMA)
            #pragma unroll
            for (int ct = 0; ct < 4; ++ct)
                xv[ct] = *(const v4f*)(x + obase
                          + (size_t)((n + 1) * 64 + ct * 16 + ln15) * Mn);
            __syncthreads();   // chunk n+1 resident
        }
    }
}

extern "C" void kernel_launch(void* const* d_in, const int* in_sizes, int n_in,
                              void* d_out, int out_size, void* d_ws, size_t ws_size,
                              hipStream_t stream) {
    const float* x    = (const float*)d_in[0];
    const float* g_w  = (const float*)d_in[1];
    const float* g_b  = (const float*)d_in[2];
    const float* th_w = (const float*)d_in[3];
    const float* th_b = (const float*)d_in[4];
    const float* w_w  = (const float*)d_in[5];
    const float* w_b  = (const float*)d_in[6];
    float* out = (float*)d_out;
    float* ws  = (float*)d_ws;

    unsigned short* wth  = (unsigned short*)(ws + OFF_WTH);
    float* tt            = ws + OFF_TT;
    float* mu            = ws + OFF_MU;
    float* beff          = ws + OFF_BEFF;
    unsigned short* wimg = (unsigned short*)(ws + OFF_WIMG);

    // zero atomic accumulators (tt and mu contiguous)
    hipMemsetAsync(tt, 0, (size_t)(Bn * ICn * ICn + Bn * ICn) * sizeof(float), stream);

    k0_prep_w<<<32, 256, 0, stream>>>(th_w, wth);
    k1_stats<<<dim3(Mn / 64, Bn), 256, 0, stream>>>(x, wth, th_b, tt, mu);
    k2_fold<<<dim3(Bn, 4), 256, 0, stream>>>(tt, mu, g_w, g_b, w_w, w_b, wimg, beff);
    k3_out<<<dim3(Mn / 64, Bn), 256, 0, stream>>>(x, wimg, beff, out);
}